// Round 2
// baseline (413.785 us; speedup 1.0000x reference)
//
#include <hip/hip_runtime.h>
#include <hip/hip_bf16.h>

#define B_   16
#define DF_  1536
#define D_   1024
#define V_   6890
#define PD_  256
#define HID_ 512
#define C_   133
#define VPAD 6912   // 54 * 128
#define CPAD 144    // 9 * 16

typedef short short8 __attribute__((ext_vector_type(8)));
typedef float float4_ __attribute__((ext_vector_type(4)));
typedef unsigned short ushort_t;

#define MFMA16 __builtin_amdgcn_mfma_f32_16x16x32_bf16

// bf16 bits -> f32 (exact)
__device__ __forceinline__ float b2f(ushort_t u) {
  union { unsigned int i; float f; } x;
  x.i = ((unsigned int)u) << 16;
  return x.f;
}
// f32 -> bf16 bits (RNE)
__device__ __forceinline__ ushort_t f2b(float f) {
  union { float f; unsigned int i; } x;
  x.f = f;
  unsigned int r = (x.i + 0x7fffu + ((x.i >> 16) & 1u)) >> 16;
  return (ushort_t)r;
}

// ---------- 1. features f32 -> f64 (so the whole mask-relevant chain is f64)
__global__ __launch_bounds__(256) void k_convd(const float* __restrict__ f,
                                               double* __restrict__ o) {
  int i = blockIdx.x * 256 + threadIdx.x;
  if (i < B_ * DF_) o[i] = (double)f[i];
}

// ---------- 2. GEMV: out[16][N] = A[16][K] @ W[K][N] (+bias), f64 accumulate
// block = 256 = 64 j-lanes x 4 k-splits; grid = (N/64, 16)
__global__ __launch_bounds__(256) void k_gemv(const double* __restrict__ A,
                                              const float* __restrict__ W,
                                              const float* __restrict__ bias,
                                              double* __restrict__ outd,
                                              float* __restrict__ outf,
                                              int K, int N) {
  int b  = blockIdx.y;
  int jl = threadIdx.x & 63;
  int ks = threadIdx.x >> 6;
  int j  = blockIdx.x * 64 + jl;
  int klen = K >> 2;
  const double* Ar = A + b * K + ks * klen;
  const float*  Wp = W + (size_t)(ks * klen) * N + j;
  double acc = 0.0;
#pragma unroll 8
  for (int kk = 0; kk < klen; ++kk)
    acc += Ar[kk] * (double)Wp[(size_t)kk * N];
  __shared__ double red[4][64];
  red[ks][jl] = acc;
  __syncthreads();
  if (ks == 0) {
    double s = red[0][jl] + red[1][jl] + red[2][jl] + red[3][jl];
    if (bias) s += (double)bias[j];
    if (outd) outd[b * N + j] = s;
    if (outf) outf[b * N + j] = (float)s;
  }
}

// ---------- 3. s = att @ W_cls + b_cls (f64); out0 = sigmoid(s); mask = s>0
// block = 256 = 32 v-lanes x 8 k-splits; all 16 batches per block.
__global__ __launch_bounds__(256) void k_cont(const double* __restrict__ att,
                                              const float* __restrict__ Wcls,
                                              const float* __restrict__ bcls,
                                              unsigned char* __restrict__ maskb,
                                              float* __restrict__ out0) {
  int vl = threadIdx.x & 31;
  int ks = threadIdx.x >> 5;             // 0..7
  int v  = blockIdx.x * 32 + vl;
  int vc = v < V_ ? v : V_ - 1;
  double acc[B_];
#pragma unroll
  for (int b = 0; b < B_; ++b) acc[b] = 0.0;
  const int klen = D_ / 8;               // 128
  int k0 = ks * klen;
  for (int kk = 0; kk < klen; ++kk) {
    int k = k0 + kk;
    double w = (double)Wcls[(size_t)k * V_ + vc];
#pragma unroll
    for (int b = 0; b < B_; ++b) acc[b] += att[b * D_ + k] * w;
  }
  __shared__ double red[8][B_][32];      // 32 KB
#pragma unroll
  for (int b = 0; b < B_; ++b) red[ks][b][vl] = acc[b];
  __syncthreads();
  int b0 = (threadIdx.x >> 5) * 2;
  for (int i = 0; i < 2; ++i) {
    int b = b0 + i;
    double s = 0.0;
#pragma unroll
    for (int q = 0; q < 8; ++q) s += red[q][b][vl];
    if (v < V_) {
      s += (double)bcls[v];
      double c = 1.0 / (1.0 + exp(-s));
      maskb[b * V_ + v] = (s > 0.0) ? 1 : 0;
      out0[b * V_ + v] = (float)c;
    }
  }
}

// ---------- 4. W_ft2^T padded to bf16: WT[c][k], c in [0,144) ----------------
__global__ __launch_bounds__(256) void k_wt(const float* __restrict__ Wft2,
                                            ushort_t* __restrict__ WT) {
  int i = blockIdx.x * 256 + threadIdx.x;
  if (i >= CPAD * HID_) return;
  int c = i >> 9, k = i & (HID_ - 1);
  WT[i] = (c < C_) ? f2b(Wft2[(size_t)k * C_ + c]) : (ushort_t)0;
}

// ---------- 5. posprojT[k_out][v] = W_ft1_bot^T @ pos_emb^T (bf16 MFMA) -----
// M = 512 (k_out), N = 6912 (v), K = 256 (pd). grid (108, 8), 4 waves/block.
__global__ __launch_bounds__(256) void k_pproj(const float* __restrict__ Wft1,
                                               const float* __restrict__ pos,
                                               ushort_t* __restrict__ PT) {
  int wave = threadIdx.x >> 6, lane = threadIdx.x & 63;
  int q = lane >> 4, l15 = lane & 15;
  int m0 = blockIdx.y * 64 + wave * 16;
  int n0 = blockIdx.x * 64;
  float4_ acc[4] = {};
  for (int kt = 0; kt < 8; ++kt) {
    int jb = kt * 32 + q * 8;
    short8 a;
#pragma unroll
    for (int jj = 0; jj < 8; ++jj)
      a[jj] = (short)f2b(Wft1[(size_t)(D_ + jb + jj) * HID_ + m0 + l15]);
#pragma unroll
    for (int nf = 0; nf < 4; ++nf) {
      int n = n0 + nf * 16 + l15;
      int nc = n < V_ ? n : V_ - 1;
      const float4_* p = (const float4_*)(pos + (size_t)nc * PD_ + jb);
      float4_ x0 = p[0], x1 = p[1];
      short8 bf;
      bf[0] = (short)f2b(x0[0]); bf[1] = (short)f2b(x0[1]);
      bf[2] = (short)f2b(x0[2]); bf[3] = (short)f2b(x0[3]);
      bf[4] = (short)f2b(x1[0]); bf[5] = (short)f2b(x1[1]);
      bf[6] = (short)f2b(x1[2]); bf[7] = (short)f2b(x1[3]);
      acc[nf] = MFMA16(a, bf, acc[nf], 0, 0, 0);
    }
  }
#pragma unroll
  for (int nf = 0; nf < 4; ++nf)
#pragma unroll
    for (int r = 0; r < 4; ++r) {
      int m = m0 + q * 4 + r;
      int n = n0 + nf * 16 + l15;
      PT[(size_t)m * VPAD + n] = f2b(acc[nf][r]);
    }
}

// ---------- 6. main: preds^T[b] = W_ft2^T @ relu(attproj[b] + posprojT) -----
// M = 144 (c), N = 128 v/block, K = 512. grid (54, 16), 4 waves/block,
// each wave: 32 v x 144 c = 9x2 C-frags.
__global__ __launch_bounds__(256) void k_main(const ushort_t* __restrict__ WT,
                                              const ushort_t* __restrict__ PT,
                                              const float* __restrict__ attproj,
                                              const unsigned char* __restrict__ maskb,
                                              const float* __restrict__ bft2,
                                              float* __restrict__ out1) {
  int b = blockIdx.y;
  int wave = threadIdx.x >> 6, lane = threadIdx.x & 63;
  int q = lane >> 4, l15 = lane & 15;
  int vbase = blockIdx.x * 128 + wave * 32;

  __shared__ float attp[HID_];
  for (int i = threadIdx.x; i < HID_; i += 256) attp[i] = attproj[b * HID_ + i];
  __syncthreads();

  float4_ acc[9][2] = {};
  for (int kt = 0; kt < 16; ++kt) {
    int kb = kt * 32 + q * 8;
    short8 bf[2];
#pragma unroll
    for (int nf = 0; nf < 2; ++nf) {
      int n = vbase + nf * 16 + l15;
#pragma unroll
      for (int jj = 0; jj < 8; ++jj) {
        int k = kb + jj;
        float h = attp[k] + b2f(PT[(size_t)k * VPAD + n]);
        bf[nf][jj] = (short)f2b(h > 0.f ? h : 0.f);
      }
    }
#pragma unroll
    for (int mt = 0; mt < 9; ++mt) {
      short8 a = *(const short8*)(WT + (size_t)(mt * 16 + l15) * HID_ + kb);
      acc[mt][0] = MFMA16(a, bf[0], acc[mt][0], 0, 0, 0);
      acc[mt][1] = MFMA16(a, bf[1], acc[mt][1], 0, 0, 0);
    }
  }

  bool mask[2];
  int  nn[2];
#pragma unroll
  for (int nf = 0; nf < 2; ++nf) {
    int n = vbase + nf * 16 + l15;
    nn[nf] = n;
    int ncl = n < V_ ? n : V_ - 1;
    mask[nf] = (n < V_) && (maskb[b * V_ + ncl] != 0);
  }
#pragma unroll
  for (int mt = 0; mt < 9; ++mt) {
#pragma unroll
    for (int r = 0; r < 4; ++r) {
      int c = mt * 16 + q * 4 + r;
      if (c < C_) {
        float bias = bft2[c];
#pragma unroll
        for (int nf = 0; nf < 2; ++nf) {
          if (nn[nf] < V_) {
            float val = mask[nf] ? acc[mt][nf][r] + bias : 0.f;
            out1[((size_t)b * C_ + c) * V_ + nn[nf]] = val;
          }
        }
      }
    }
  }
}

extern "C" void kernel_launch(void* const* d_in, const int* in_sizes, int n_in,
                              void* d_out, int out_size, void* d_ws, size_t ws_size,
                              hipStream_t stream) {
  const float* features  = (const float*)d_in[0];
  // d_in[1], d_in[2] (W_scene, b_scene) and d_in[5], d_in[6] (Wq, Wk) are
  // mathematically dead: softmax over a length-1 sequence is identically 1,
  // so att = (part @ Wv) @ Wo regardless of q/k.
  const float* W_contact = (const float*)d_in[3];
  const float* b_contact = (const float*)d_in[4];
  const float* Wv        = (const float*)d_in[7];
  const float* Wo        = (const float*)d_in[8];
  const float* W_cls     = (const float*)d_in[9];
  const float* b_cls     = (const float*)d_in[10];
  const float* pos_emb   = (const float*)d_in[11];
  const float* W_ft1     = (const float*)d_in[12];
  const float* b_ft1     = (const float*)d_in[13];
  const float* W_ft2     = (const float*)d_in[14];
  const float* b_ft2     = (const float*)d_in[15];

  char* ws = (char*)d_ws;
  double*        featd = (double*)(ws);               // 196608 B
  double*        part  = (double*)(ws + 196608);      // 131072 B
  double*        vv    = (double*)(ws + 327680);      // 131072 B
  double*        att   = (double*)(ws + 458752);      // 131072 B
  float*         attpj = (float*)(ws + 589824);       //  32768 B
  unsigned char* maskb = (unsigned char*)(ws + 622592); // 110240 B
  ushort_t*      wt    = (ushort_t*)(ws + 732928);    // 147456 B
  ushort_t*      pt    = (ushort_t*)(ws + 880384);    // 7077888 B -> ~7.96 MB

  float* out0 = (float*)d_out;
  float* out1 = out0 + (size_t)B_ * V_;

  k_convd<<<96, 256, 0, stream>>>(features, featd);
  // part = features @ W_contact + b_contact       [16,1536]@[1536,1024], f64
  k_gemv<<<dim3(16, 16), 256, 0, stream>>>(featd, W_contact, b_contact, part, nullptr, DF_, D_);
  // v = part @ Wv                                 [16,1024]@[1024,1024], f64
  k_gemv<<<dim3(16, 16), 256, 0, stream>>>(part, Wv, nullptr, vv, nullptr, D_, D_);
  // att = v @ Wo  (softmax over 1 token == 1)
  k_gemv<<<dim3(16, 16), 256, 0, stream>>>(vv, Wo, nullptr, att, nullptr, D_, D_);
  // attproj = att @ W_ft1[:1024] + b_ft1          [16,1024]@[1024,512] -> f32
  k_gemv<<<dim3(8, 16), 256, 0, stream>>>(att, W_ft1, b_ft1, nullptr, attpj, D_, HID_);
  // cont (f64 dot for exact mask) -> out0 + mask
  k_cont<<<216, 256, 0, stream>>>(att, W_cls, b_cls, maskb, out0);
  // W_ft2^T padded, bf16
  k_wt<<<288, 256, 0, stream>>>(W_ft2, wt);
  // posprojT = (pos_emb @ W_ft1[1024:])^T via bf16 MFMA
  k_pproj<<<dim3(108, 8), 256, 0, stream>>>(W_ft1, pos_emb, pt);
  // semantic_cont
  k_main<<<dim3(54, 16), 256, 0, stream>>>(wt, pt, attpj, maskb, b_ft2, out1);
}

// Round 4
// 354.554 us; speedup vs baseline: 1.1671x; 1.1671x over previous
//
#include <hip/hip_runtime.h>
#include <hip/hip_bf16.h>

#define B_   16
#define DF_  1536
#define D_   1024
#define V_   6890
#define PD_  256
#define HID_ 512
#define C_   133
#define VPAD 6912   // 54 * 128
#define CPAD 144    // 9 * 16

typedef short short8 __attribute__((ext_vector_type(8)));
typedef int   int4_  __attribute__((ext_vector_type(4)));
typedef float float4_ __attribute__((ext_vector_type(4)));
typedef unsigned short ushort_t;

#define MFMA16 __builtin_amdgcn_mfma_f32_16x16x32_bf16

// bf16 bits -> f32 (exact)
__device__ __forceinline__ float b2f(ushort_t u) {
  union { unsigned int i; float f; } x;
  x.i = ((unsigned int)u) << 16;
  return x.f;
}
// f32 -> bf16 bits (RNE, scalar)
__device__ __forceinline__ ushort_t f2b(float f) {
  union { float f; unsigned int i; } x;
  x.f = f;
  unsigned int r = (x.i + 0x7fffu + ((x.i >> 16) & 1u)) >> 16;
  return (ushort_t)r;
}
// two f32 -> packed bf16x2 (emits v_cvt_pk_bf16_f32)
__device__ __forceinline__ unsigned int f22u(float h0, float h1) {
  __hip_bfloat162 hb = __float22bfloat162_rn(make_float2(h0, h1));
  unsigned int u;
  __builtin_memcpy(&u, &hb, sizeof(u));   // not bit_cast: bf162 isn't trivially copyable
  return u;
}

// ---------- GEMV (f32 A): out[16][N] = A[16][K] @ W[K][N] (+bias), f64 acc
// block 256 = 16 j x 16 ksplit; grid (N/16, B)
__global__ __launch_bounds__(256) void k_gemv_fA(const float* __restrict__ A,
                                                 const float* __restrict__ W,
                                                 const float* __restrict__ bias,
                                                 double* __restrict__ outd,
                                                 float* __restrict__ outf,
                                                 int K, int N) {
  int jl = threadIdx.x & 15, ks = threadIdx.x >> 4;
  int b  = blockIdx.y;
  int j  = blockIdx.x * 16 + jl;
  int klen = K >> 4;
  const float* Ar = A + b * K + ks * klen;
  const float* Wp = W + (size_t)(ks * klen) * N + j;
  double acc = 0.0;
#pragma unroll 8
  for (int kk = 0; kk < klen; ++kk)
    acc += (double)Ar[kk] * (double)Wp[(size_t)kk * N];
  __shared__ double red[16][16];
  red[ks][jl] = acc;
  __syncthreads();
  if (threadIdx.x < 16) {
    int jj = blockIdx.x * 16 + threadIdx.x;
    double s = 0.0;
#pragma unroll
    for (int q = 0; q < 16; ++q) s += red[q][threadIdx.x];
    if (bias) s += (double)bias[jj];
    if (outd) outd[b * N + jj] = s;
    if (outf) outf[b * N + jj] = (float)s;
  }
}

// ---------- GEMV (f64 A): same, A is double
__global__ __launch_bounds__(256) void k_gemv_dA(const double* __restrict__ A,
                                                 const float* __restrict__ W,
                                                 const float* __restrict__ bias,
                                                 double* __restrict__ outd,
                                                 float* __restrict__ outf,
                                                 int K, int N) {
  int jl = threadIdx.x & 15, ks = threadIdx.x >> 4;
  int b  = blockIdx.y;
  int j  = blockIdx.x * 16 + jl;
  int klen = K >> 4;
  const double* Ar = A + b * K + ks * klen;
  const float*  Wp = W + (size_t)(ks * klen) * N + j;
  double acc = 0.0;
#pragma unroll 8
  for (int kk = 0; kk < klen; ++kk)
    acc += Ar[kk] * (double)Wp[(size_t)kk * N];
  __shared__ double red[16][16];
  red[ks][jl] = acc;
  __syncthreads();
  if (threadIdx.x < 16) {
    int jj = blockIdx.x * 16 + threadIdx.x;
    double s = 0.0;
#pragma unroll
    for (int q = 0; q < 16; ++q) s += red[q][threadIdx.x];
    if (bias) s += (double)bias[jj];
    if (outd) outd[b * N + jj] = s;
    if (outf) outf[b * N + jj] = (float)s;
  }
}

// ---------- s = att @ W_cls + b_cls (f64); out0 = sigmoid(s); mask = s>0
// block 256 = 16 v x 16 ksplit; grid 432; all 16 b per block.
__global__ __launch_bounds__(256) void k_cont(const double* __restrict__ att,
                                              const float* __restrict__ Wcls,
                                              const float* __restrict__ bcls,
                                              unsigned char* __restrict__ maskb,
                                              float* __restrict__ out0) {
  int vl = threadIdx.x & 15, ks = threadIdx.x >> 4;
  int v  = blockIdx.x * 16 + vl;
  int vc = v < V_ ? v : V_ - 1;
  double acc[B_];
#pragma unroll
  for (int b = 0; b < B_; ++b) acc[b] = 0.0;
  int k0 = ks * 64;
  for (int kk = 0; kk < 64; ++kk) {
    int k = k0 + kk;
    double w = (double)Wcls[(size_t)k * V_ + vc];
#pragma unroll
    for (int b = 0; b < B_; ++b) acc[b] += att[b * D_ + k] * w;
  }
  __shared__ double red[16][B_][16];     // 32 KB
#pragma unroll
  for (int b = 0; b < B_; ++b) red[ks][b][vl] = acc[b];
  __syncthreads();
  int b = threadIdx.x >> 4;
  double s = 0.0;
#pragma unroll
  for (int q = 0; q < 16; ++q) s += red[q][b][vl];
  if (v < V_) {
    s += (double)bcls[v];
    maskb[b * V_ + v] = (s > 0.0) ? 1 : 0;
    out0[b * V_ + v] = (float)(1.0 / (1.0 + exp(-s)));
  }
}

// ---------- W_ft2^T padded to bf16: WT[c][k], c in [0,144) ------------------
__global__ __launch_bounds__(256) void k_wt(const float* __restrict__ Wft2,
                                            ushort_t* __restrict__ WT) {
  int i = blockIdx.x * 256 + threadIdx.x;
  if (i >= CPAD * HID_) return;
  int c = i >> 9, k = i & (HID_ - 1);
  WT[i] = (c < C_) ? f2b(Wft2[(size_t)k * C_ + c]) : (ushort_t)0;
}

// ---------- WbT[k_out][pd] = bf16(Wft1[1024+pd][k_out]) ---------------------
__global__ __launch_bounds__(256) void k_prep_wbt(const float* __restrict__ Wft1,
                                                  ushort_t* __restrict__ WbT) {
  int i = blockIdx.x * 256 + threadIdx.x;     // exact: 512*256 threads
  int k  = i & (HID_ - 1);
  int pd = i >> 9;
  WbT[(size_t)k * PD_ + pd] = f2b(Wft1[(size_t)(D_ + pd) * HID_ + k]);
}

// ---------- PP[v][k_out] = pos_emb[v] @ Wft1_bot  (bf16 MFMA) ---------------
// M = v (16/wave), N = k_out (64/wave), K = pd = 256. grid (108, 8).
__global__ __launch_bounds__(256) void k_pproj(const float* __restrict__ pos,
                                               const ushort_t* __restrict__ WbT,
                                               ushort_t* __restrict__ PP) {
  int wave = threadIdx.x >> 6, lane = threadIdx.x & 63;
  int q = lane >> 4, l15 = lane & 15;
  int m0 = blockIdx.x * 64 + wave * 16;        // v tile
  int n0 = blockIdx.y * 64;                    // k_out tile
  int vc = m0 + l15; vc = vc < V_ ? vc : V_ - 1;
  float4_ acc[4] = {};
  for (int kt = 0; kt < 8; ++kt) {
    int jb = kt * 32 + q * 8;                  // pd offset
    const float* pr = pos + (size_t)vc * PD_ + jb;
    float4_ x0 = *(const float4_*)pr;
    float4_ x1 = *(const float4_*)(pr + 4);
    int4_ iv;
    iv[0] = f22u(x0[0], x0[1]);
    iv[1] = f22u(x0[2], x0[3]);
    iv[2] = f22u(x1[0], x1[1]);
    iv[3] = f22u(x1[2], x1[3]);
    short8 a;
    __builtin_memcpy(&a, &iv, sizeof(a));
#pragma unroll
    for (int nf = 0; nf < 4; ++nf) {
      int n = n0 + nf * 16 + l15;
      short8 bfr = *(const short8*)(WbT + (size_t)n * PD_ + jb);
      acc[nf] = MFMA16(a, bfr, acc[nf], 0, 0, 0);
    }
  }
#pragma unroll
  for (int nf = 0; nf < 4; ++nf)
#pragma unroll
    for (int r = 0; r < 4; ++r) {
      int v = m0 + q * 4 + r;
      int k = n0 + nf * 16 + l15;
      PP[(size_t)v * HID_ + k] = f2b(acc[nf][r]);
    }
}

// ---------- main: preds^T[b] = W_ft2^T @ relu(attproj[b] + PP^T) ------------
// M = 144 (c), N = 128 v/block, K = 512. grid (54, 16), 4 waves/block.
__global__ __launch_bounds__(256) void k_main(const ushort_t* __restrict__ WT,
                                              const ushort_t* __restrict__ PP,
                                              const float* __restrict__ attproj,
                                              const unsigned char* __restrict__ maskb,
                                              const float* __restrict__ bft2,
                                              float* __restrict__ out1) {
  int b = blockIdx.y;
  int wave = threadIdx.x >> 6, lane = threadIdx.x & 63;
  int q = lane >> 4, l15 = lane & 15;
  int vbase = blockIdx.x * 128 + wave * 32;

  __shared__ float attp[HID_];
  for (int i = threadIdx.x; i < HID_; i += 256) attp[i] = attproj[b * HID_ + i];
  __syncthreads();

  float4_ acc[9][2] = {};
  for (int kt = 0; kt < 16; ++kt) {
    int kb = kt * 32 + q * 8;
    float attk[8];
#pragma unroll
    for (int jj = 0; jj < 8; ++jj) attk[jj] = attp[kb + jj];
    short8 bf[2];
#pragma unroll
    for (int nf = 0; nf < 2; ++nf) {
      int n = vbase + nf * 16 + l15;
      short8 p = *(const short8*)(PP + (size_t)n * HID_ + kb);
      int4_ iv;
#pragma unroll
      for (int jj = 0; jj < 8; jj += 2) {
        float h0 = attk[jj]     + b2f((ushort_t)p[jj]);
        float h1 = attk[jj + 1] + b2f((ushort_t)p[jj + 1]);
        h0 = h0 > 0.f ? h0 : 0.f;
        h1 = h1 > 0.f ? h1 : 0.f;
        iv[jj >> 1] = f22u(h0, h1);
      }
      __builtin_memcpy(&bf[nf], &iv, sizeof(bf[nf]));
    }
#pragma unroll
    for (int mt = 0; mt < 9; ++mt) {
      short8 a = *(const short8*)(WT + (size_t)(mt * 16 + l15) * HID_ + kb);
      acc[mt][0] = MFMA16(a, bf[0], acc[mt][0], 0, 0, 0);
      acc[mt][1] = MFMA16(a, bf[1], acc[mt][1], 0, 0, 0);
    }
  }

  bool mask[2];
  int  nn[2];
#pragma unroll
  for (int nf = 0; nf < 2; ++nf) {
    int n = vbase + nf * 16 + l15;
    nn[nf] = n;
    int ncl = n < V_ ? n : V_ - 1;
    mask[nf] = (n < V_) && (maskb[b * V_ + ncl] != 0);
  }
#pragma unroll
  for (int mt = 0; mt < 9; ++mt) {
#pragma unroll
    for (int r = 0; r < 4; ++r) {
      int c = mt * 16 + q * 4 + r;
      if (c < C_) {
        float bias = bft2[c];
#pragma unroll
        for (int nf = 0; nf < 2; ++nf) {
          if (nn[nf] < V_) {
            float val = mask[nf] ? acc[mt][nf][r] + bias : 0.f;
            out1[((size_t)b * C_ + c) * V_ + nn[nf]] = val;
          }
        }
      }
    }
  }
}

extern "C" void kernel_launch(void* const* d_in, const int* in_sizes, int n_in,
                              void* d_out, int out_size, void* d_ws, size_t ws_size,
                              hipStream_t stream) {
  const float* features  = (const float*)d_in[0];
  // d_in[1], d_in[2] (W_scene, b_scene) and d_in[5], d_in[6] (Wq, Wk) are
  // mathematically dead: softmax over a length-1 sequence is identically 1,
  // so att = (part @ Wv) @ Wo regardless of q/k.
  const float* W_contact = (const float*)d_in[3];
  const float* b_contact = (const float*)d_in[4];
  const float* Wv        = (const float*)d_in[7];
  const float* Wo        = (const float*)d_in[8];
  const float* W_cls     = (const float*)d_in[9];
  const float* b_cls     = (const float*)d_in[10];
  const float* pos_emb   = (const float*)d_in[11];
  const float* W_ft1     = (const float*)d_in[12];
  const float* b_ft1     = (const float*)d_in[13];
  const float* W_ft2     = (const float*)d_in[14];
  const float* b_ft2     = (const float*)d_in[15];

  char* ws = (char*)d_ws;
  // part (dead after gemv2) shares offset 0 with maskb (written later by k_cont)
  double*        part  = (double*)(ws);                 // 131072 B, dead early
  unsigned char* maskb = (unsigned char*)(ws);          // 110240 B, written later
  double*        vv    = (double*)(ws + 131072);        // 131072 B
  double*        att   = (double*)(ws + 262144);        // 131072 B
  float*         attpj = (float*)(ws + 393216);         //  32768 B
  ushort_t*      wt    = (ushort_t*)(ws + 425984);      // 147456 B
  ushort_t*      wbt   = (ushort_t*)(ws + 573440);      // 262144 B
  ushort_t*      pp    = (ushort_t*)(ws + 835584);      // 7077888 B -> 7.91 MB total

  float* out0 = (float*)d_out;
  float* out1 = out0 + (size_t)B_ * V_;

  // independent prep
  k_wt<<<288, 256, 0, stream>>>(W_ft2, wt);
  k_prep_wbt<<<512, 256, 0, stream>>>(W_ft1, wbt);
  k_pproj<<<dim3(108, 8), 256, 0, stream>>>(pos_emb, wbt, pp);
  // dependent chain (f64 accumulate throughout for exact mask)
  k_gemv_fA<<<dim3(64, 16), 256, 0, stream>>>(features, W_contact, b_contact, part, nullptr, DF_, D_);
  k_gemv_dA<<<dim3(64, 16), 256, 0, stream>>>(part, Wv, nullptr, vv, nullptr, D_, D_);
  k_gemv_dA<<<dim3(64, 16), 256, 0, stream>>>(vv, Wo, nullptr, att, nullptr, D_, D_);
  k_gemv_dA<<<dim3(32, 16), 256, 0, stream>>>(att, W_ft1, b_ft1, nullptr, attpj, D_, HID_);
  k_cont<<<432, 256, 0, stream>>>(att, W_cls, b_cls, maskb, out0);
  // semantic_cont
  k_main<<<dim3(54, 16), 256, 0, stream>>>(wt, pp, attpj, maskb, b_ft2, out1);
}

// Round 5
// 282.817 us; speedup vs baseline: 1.4631x; 1.2536x over previous
//
#include <hip/hip_runtime.h>
#include <hip/hip_bf16.h>

#define B_   16
#define DF_  1536
#define D_   1024
#define V_   6890
#define PD_  256
#define HID_ 512
#define C_   133
#define VPAD 6912   // 54 * 128
#define CPAD 144    // 9 * 16

typedef short short8 __attribute__((ext_vector_type(8)));
typedef float float4_ __attribute__((ext_vector_type(4)));
typedef unsigned short ushort_t;

#define MFMA16 __builtin_amdgcn_mfma_f32_16x16x32_bf16

// bf16 bits -> f32 (exact)
__device__ __forceinline__ float b2f(ushort_t u) {
  union { unsigned int i; float f; } x;
  x.i = ((unsigned int)u) << 16;
  return x.f;
}
// f32 -> bf16 bits (RNE, scalar)
__device__ __forceinline__ ushort_t f2b(float f) {
  union { float f; unsigned int i; } x;
  x.f = f;
  unsigned int r = (x.i + 0x7fffu + ((x.i >> 16) & 1u)) >> 16;
  return (ushort_t)r;
}
// two f32 -> packed bf16x2 (emits v_cvt_pk_bf16_f32)
__device__ __forceinline__ unsigned int f22u(float h0, float h1) {
  __hip_bfloat162 hb = __float22bfloat162_rn(make_float2(h0, h1));
  unsigned int u;
  __builtin_memcpy(&u, &hb, sizeof(u));
  return u;
}

// ---------- GEMV (f32 A): out[16][N] = A[16][K] @ W[K][N] (+bias), f64 acc
__global__ __launch_bounds__(256) void k_gemv_fA(const float* __restrict__ A,
                                                 const float* __restrict__ W,
                                                 const float* __restrict__ bias,
                                                 double* __restrict__ outd,
                                                 float* __restrict__ outf,
                                                 int K, int N) {
  int jl = threadIdx.x & 15, ks = threadIdx.x >> 4;
  int b  = blockIdx.y;
  int j  = blockIdx.x * 16 + jl;
  int klen = K >> 4;
  const float* Ar = A + b * K + ks * klen;
  const float* Wp = W + (size_t)(ks * klen) * N + j;
  double acc = 0.0;
#pragma unroll 8
  for (int kk = 0; kk < klen; ++kk)
    acc += (double)Ar[kk] * (double)Wp[(size_t)kk * N];
  __shared__ double red[16][16];
  red[ks][jl] = acc;
  __syncthreads();
  if (threadIdx.x < 16) {
    int jj = blockIdx.x * 16 + threadIdx.x;
    double s = 0.0;
#pragma unroll
    for (int q = 0; q < 16; ++q) s += red[q][threadIdx.x];
    if (bias) s += (double)bias[jj];
    if (outd) outd[b * N + jj] = s;
    if (outf) outf[b * N + jj] = (float)s;
  }
}

// ---------- GEMV (f64 A)
__global__ __launch_bounds__(256) void k_gemv_dA(const double* __restrict__ A,
                                                 const float* __restrict__ W,
                                                 const float* __restrict__ bias,
                                                 double* __restrict__ outd,
                                                 float* __restrict__ outf,
                                                 int K, int N) {
  int jl = threadIdx.x & 15, ks = threadIdx.x >> 4;
  int b  = blockIdx.y;
  int j  = blockIdx.x * 16 + jl;
  int klen = K >> 4;
  const double* Ar = A + b * K + ks * klen;
  const float*  Wp = W + (size_t)(ks * klen) * N + j;
  double acc = 0.0;
#pragma unroll 8
  for (int kk = 0; kk < klen; ++kk)
    acc += Ar[kk] * (double)Wp[(size_t)kk * N];
  __shared__ double red[16][16];
  red[ks][jl] = acc;
  __syncthreads();
  if (threadIdx.x < 16) {
    int jj = blockIdx.x * 16 + threadIdx.x;
    double s = 0.0;
#pragma unroll
    for (int q = 0; q < 16; ++q) s += red[q][threadIdx.x];
    if (bias) s += (double)bias[jj];
    if (outd) outd[b * N + jj] = s;
    if (outf) outf[b * N + jj] = (float)s;
  }
}

// ---------- s = att @ W_cls + b_cls (f64); out0 = sigmoid(s); mask = s>0
__global__ __launch_bounds__(256) void k_cont(const double* __restrict__ att,
                                              const float* __restrict__ Wcls,
                                              const float* __restrict__ bcls,
                                              unsigned char* __restrict__ maskb,
                                              float* __restrict__ out0) {
  int vl = threadIdx.x & 15, ks = threadIdx.x >> 4;
  int v  = blockIdx.x * 16 + vl;
  int vc = v < V_ ? v : V_ - 1;
  double acc[B_];
#pragma unroll
  for (int b = 0; b < B_; ++b) acc[b] = 0.0;
  int k0 = ks * 64;
  for (int kk = 0; kk < 64; ++kk) {
    int k = k0 + kk;
    double w = (double)Wcls[(size_t)k * V_ + vc];
#pragma unroll
    for (int b = 0; b < B_; ++b) acc[b] += att[b * D_ + k] * w;
  }
  __shared__ double red[16][B_][16];
#pragma unroll
  for (int b = 0; b < B_; ++b) red[ks][b][vl] = acc[b];
  __syncthreads();
  int b = threadIdx.x >> 4;
  double s = 0.0;
#pragma unroll
  for (int q = 0; q < 16; ++q) s += red[q][b][vl];
  if (v < V_) {
    s += (double)bcls[v];
    maskb[b * V_ + v] = (s > 0.0) ? 1 : 0;
    out0[b * V_ + v] = (float)(1.0 / (1.0 + exp(-s)));
  }
}

// ---------- merged prep: WT (padded W_ft2^T) + WbT (W_ft1 bottom, transposed)
__global__ __launch_bounds__(256) void k_prep(const float* __restrict__ Wft2,
                                              const float* __restrict__ Wft1,
                                              ushort_t* __restrict__ WT,
                                              ushort_t* __restrict__ WbT) {
  int i = blockIdx.x * 256 + threadIdx.x;
  if (i < CPAD * HID_) {
    int c = i >> 9, k = i & (HID_ - 1);
    WT[i] = (c < C_) ? f2b(Wft2[(size_t)k * C_ + c]) : (ushort_t)0;
  } else {
    int j = i - CPAD * HID_;
    if (j < HID_ * PD_) {
      int k = j & (HID_ - 1), pd = j >> 9;
      WbT[(size_t)k * PD_ + pd] = f2b(Wft1[(size_t)(D_ + pd) * HID_ + k]);
    }
  }
}

// ---------- PP[v][k_out] = pos_emb[v] @ Wft1_bot (bf16 MFMA, LDS-staged pos)
// grid (108, 8); block 256 = 4 waves; block v-tile 64, k_out tile 64.
#define LDSROW 264   // 256 + 8 bf16 pad -> rows shift 4 banks, 2-way max (free)
__global__ __launch_bounds__(256) void k_pproj(const float* __restrict__ pos,
                                               const ushort_t* __restrict__ WbT,
                                               ushort_t* __restrict__ PP) {
  __shared__ ushort_t sp[64 * LDSROW];   // 33792 B
  int v0 = blockIdx.x * 64;
  // stage 64 rows x 256 pd as bf16, coalesced float4 reads
#pragma unroll
  for (int k = 0; k < 16; ++k) {
    int flat4 = k * 256 + threadIdx.x;          // 4096 float4 tiles
    int row = flat4 >> 6, col4 = flat4 & 63;
    int vr = v0 + row; vr = vr < V_ ? vr : V_ - 1;
    float4_ x = *(const float4_*)(pos + (size_t)vr * PD_ + col4 * 4);
    unsigned int* dst = (unsigned int*)&sp[row * LDSROW + col4 * 4];
    dst[0] = f22u(x[0], x[1]);
    dst[1] = f22u(x[2], x[3]);
  }
  __syncthreads();

  int wave = threadIdx.x >> 6, lane = threadIdx.x & 63;
  int q = lane >> 4, l15 = lane & 15;
  int n0 = blockIdx.y * 64;
  float4_ acc[4] = {};
  for (int kt = 0; kt < 8; ++kt) {
    int jb = kt * 32 + q * 8;
    short8 a = *(const short8*)&sp[(wave * 16 + l15) * LDSROW + jb];
#pragma unroll
    for (int nf = 0; nf < 4; ++nf) {
      int n = n0 + nf * 16 + l15;
      short8 bfr = *(const short8*)(WbT + (size_t)n * PD_ + jb);
      acc[nf] = MFMA16(a, bfr, acc[nf], 0, 0, 0);
    }
  }
  int v0w = v0 + wave * 16 + q * 4;
#pragma unroll
  for (int nf = 0; nf < 4; ++nf)
#pragma unroll
    for (int r = 0; r < 4; ++r)
      PP[(size_t)(v0w + r) * HID_ + (n0 + nf * 16 + l15)] = f2b(acc[nf][r]);
}

// ---------- main: preds^T[b] = W_ft2^T @ relu(attproj[b] + PP^T) ------------
// grid (54, 8): v-tile 128, batch-PAIR per block. 4 waves; wave = 32 v x 144 c x 2 b.
__global__ __launch_bounds__(256, 2) void k_main(const ushort_t* __restrict__ WT,
                                                 const ushort_t* __restrict__ PP,
                                                 const float* __restrict__ attproj,
                                                 const unsigned char* __restrict__ maskb,
                                                 const float* __restrict__ bft2,
                                                 float* __restrict__ out1) {
  int b0 = blockIdx.y * 2;
  int wave = threadIdx.x >> 6, lane = threadIdx.x & 63;
  int q = lane >> 4, l15 = lane & 15;
  int vbase = blockIdx.x * 128 + wave * 32;

  __shared__ float attp[2][HID_];
  for (int i = threadIdx.x; i < 2 * HID_; i += 256)
    attp[i >> 9][i & (HID_ - 1)] = attproj[(b0 + (i >> 9)) * HID_ + (i & (HID_ - 1))];
  __syncthreads();

  const ushort_t* pbase0 = PP + (size_t)(vbase + l15) * HID_;
  const ushort_t* pbase1 = PP + (size_t)(vbase + 16 + l15) * HID_;

  float4_ acc[2][9][2] = {};             // [bb][mt][nf]
  short8 pcur[2];
  pcur[0] = *(const short8*)(pbase0 + q * 8);
  pcur[1] = *(const short8*)(pbase1 + q * 8);

  for (int kt = 0; kt < 16; ++kt) {
    int kb = kt * 32 + q * 8;
    short8 pnext[2] = {pcur[0], pcur[1]};
    if (kt < 15) {                        // prefetch next K-tile's PP frags
      pnext[0] = *(const short8*)(pbase0 + kb + 32);
      pnext[1] = *(const short8*)(pbase1 + kb + 32);
    }
    // PP bf16 -> f32 once, shared across both batches
    float pf[2][8];
#pragma unroll
    for (int nf = 0; nf < 2; ++nf)
#pragma unroll
      for (int jj = 0; jj < 8; ++jj)
        pf[nf][jj] = b2f((ushort_t)pcur[nf][jj]);
    float af[2][8];
#pragma unroll
    for (int bb = 0; bb < 2; ++bb) {
      float4_ a0 = *(const float4_*)&attp[bb][kb];
      float4_ a1 = *(const float4_*)&attp[bb][kb + 4];
#pragma unroll
      for (int e = 0; e < 4; ++e) { af[bb][e] = a0[e]; af[bb][4 + e] = a1[e]; }
    }
    short8 bfr[2][2];
#pragma unroll
    for (int bb = 0; bb < 2; ++bb)
#pragma unroll
      for (int nf = 0; nf < 2; ++nf) {
        unsigned int uu[4];
#pragma unroll
        for (int jj = 0; jj < 8; jj += 2) {
          float h0 = af[bb][jj]     + pf[nf][jj];
          float h1 = af[bb][jj + 1] + pf[nf][jj + 1];
          h0 = h0 > 0.f ? h0 : 0.f;
          h1 = h1 > 0.f ? h1 : 0.f;
          uu[jj >> 1] = f22u(h0, h1);
        }
        __builtin_memcpy(&bfr[bb][nf], uu, 16);
      }
#pragma unroll
    for (int mt = 0; mt < 9; ++mt) {
      short8 a = *(const short8*)(WT + (size_t)(mt * 16 + l15) * HID_ + kb);
      acc[0][mt][0] = MFMA16(a, bfr[0][0], acc[0][mt][0], 0, 0, 0);
      acc[0][mt][1] = MFMA16(a, bfr[0][1], acc[0][mt][1], 0, 0, 0);
      acc[1][mt][0] = MFMA16(a, bfr[1][0], acc[1][mt][0], 0, 0, 0);
      acc[1][mt][1] = MFMA16(a, bfr[1][1], acc[1][mt][1], 0, 0, 0);
    }
    pcur[0] = pnext[0];
    pcur[1] = pnext[1];
  }

  bool mk[2][2];
  int  nn[2];
#pragma unroll
  for (int nf = 0; nf < 2; ++nf) {
    int n = vbase + nf * 16 + l15;
    nn[nf] = n;
    int ncl = n < V_ ? n : V_ - 1;
    mk[0][nf] = (n < V_) && (maskb[(b0 + 0) * V_ + ncl] != 0);
    mk[1][nf] = (n < V_) && (maskb[(b0 + 1) * V_ + ncl] != 0);
  }
#pragma unroll
  for (int bb = 0; bb < 2; ++bb) {
    float* ob = out1 + (size_t)(b0 + bb) * C_ * V_;
#pragma unroll
    for (int mt = 0; mt < 9; ++mt)
#pragma unroll
      for (int r = 0; r < 4; ++r) {
        int c = mt * 16 + q * 4 + r;
        if (c < C_) {
          float bias = bft2[c];
#pragma unroll
          for (int nf = 0; nf < 2; ++nf)
            if (nn[nf] < V_) {
              float val = mk[bb][nf] ? acc[bb][mt][nf][r] + bias : 0.f;
              ob[(size_t)c * V_ + nn[nf]] = val;
            }
        }
      }
  }
}

extern "C" void kernel_launch(void* const* d_in, const int* in_sizes, int n_in,
                              void* d_out, int out_size, void* d_ws, size_t ws_size,
                              hipStream_t stream) {
  const float* features  = (const float*)d_in[0];
  // W_scene/b_scene/Wq/Wk are mathematically dead: softmax over a length-1
  // sequence is identically 1, so att = (part @ Wv) @ Wo.
  const float* W_contact = (const float*)d_in[3];
  const float* b_contact = (const float*)d_in[4];
  const float* Wv        = (const float*)d_in[7];
  const float* Wo        = (const float*)d_in[8];
  const float* W_cls     = (const float*)d_in[9];
  const float* b_cls     = (const float*)d_in[10];
  const float* pos_emb   = (const float*)d_in[11];
  const float* W_ft1     = (const float*)d_in[12];
  const float* b_ft1     = (const float*)d_in[13];
  const float* W_ft2     = (const float*)d_in[14];
  const float* b_ft2     = (const float*)d_in[15];

  char* ws = (char*)d_ws;
  double*        part  = (double*)(ws);                 // dead after 2nd gemv
  unsigned char* maskb = (unsigned char*)(ws);          // written later by k_cont
  double*        vv    = (double*)(ws + 131072);
  double*        att   = (double*)(ws + 262144);
  float*         attpj = (float*)(ws + 393216);
  ushort_t*      wt    = (ushort_t*)(ws + 425984);      // 147456 B
  ushort_t*      wbt   = (ushort_t*)(ws + 573440);      // 262144 B
  ushort_t*      pp    = (ushort_t*)(ws + 835584);      // 7077888 B -> ~7.9 MB

  float* out0 = (float*)d_out;
  float* out1 = out0 + (size_t)B_ * V_;

  k_prep<<<800, 256, 0, stream>>>(W_ft2, W_ft1, wt, wbt);
  k_pproj<<<dim3(108, 8), 256, 0, stream>>>(pos_emb, wbt, pp);
  k_gemv_fA<<<dim3(64, 16), 256, 0, stream>>>(features, W_contact, b_contact, part, nullptr, DF_, D_);
  k_gemv_dA<<<dim3(64, 16), 256, 0, stream>>>(part, Wv, nullptr, vv, nullptr, D_, D_);
  k_gemv_dA<<<dim3(64, 16), 256, 0, stream>>>(vv, Wo, nullptr, att, nullptr, D_, D_);
  k_gemv_dA<<<dim3(32, 16), 256, 0, stream>>>(att, W_ft1, b_ft1, nullptr, attpj, D_, HID_);
  k_cont<<<432, 256, 0, stream>>>(att, W_cls, b_cls, maskb, out0);
  k_main<<<dim3(54, 8), 256, 0, stream>>>(wt, pp, attpj, maskb, b_ft2, out1);
}

// Round 6
// 268.485 us; speedup vs baseline: 1.5412x; 1.0534x over previous
//
#include <hip/hip_runtime.h>
#include <hip/hip_bf16.h>

#define B_   16
#define DF_  1536
#define D_   1024
#define V_   6890
#define PD_  256
#define HID_ 512
#define C_   133
#define VPAD 6912   // 54 * 128
#define CPAD 144    // 9 * 16

typedef short short8 __attribute__((ext_vector_type(8)));
typedef float float4_ __attribute__((ext_vector_type(4)));
typedef unsigned short ushort_t;

#define MFMA16 __builtin_amdgcn_mfma_f32_16x16x32_bf16

__device__ __forceinline__ float b2f(ushort_t u) {
  union { unsigned int i; float f; } x;
  x.i = ((unsigned int)u) << 16;
  return x.f;
}
__device__ __forceinline__ ushort_t f2b(float f) {
  union { float f; unsigned int i; } x;
  x.f = f;
  unsigned int r = (x.i + 0x7fffu + ((x.i >> 16) & 1u)) >> 16;
  return (ushort_t)r;
}
__device__ __forceinline__ unsigned int f22u(float h0, float h1) {
  __hip_bfloat162 hb = __float22bfloat162_rn(make_float2(h0, h1));
  unsigned int u;
  __builtin_memcpy(&u, &hb, sizeof(u));
  return u;
}

// ---------- GEMV (f32 A): out[16][N] = A[16][K] @ W[K][N] (+bias), f64 acc
// A row staged in LDS; inner loop = W loads only (unroll 8 = 8 outstanding).
__global__ __launch_bounds__(256) void k_gemv_fA(const float* __restrict__ A,
                                                 const float* __restrict__ W,
                                                 const float* __restrict__ bias,
                                                 double* __restrict__ outd,
                                                 float* __restrict__ outf,
                                                 int K, int N) {
  __shared__ double sA[DF_];             // 12 KB (max K)
  int b = blockIdx.y;
  for (int i = threadIdx.x; i < K; i += 256) sA[i] = (double)A[b * K + i];
  __syncthreads();
  int jl = threadIdx.x & 15, ks = threadIdx.x >> 4;
  int j  = blockIdx.x * 16 + jl;
  int klen = K >> 4;
  const double* Ar = sA + ks * klen;
  const float*  Wp = W + (size_t)(ks * klen) * N + j;
  double acc = 0.0;
#pragma unroll 8
  for (int kk = 0; kk < klen; ++kk)
    acc += Ar[kk] * (double)Wp[(size_t)kk * N];
  __shared__ double red[16][16];
  red[ks][jl] = acc;
  __syncthreads();
  if (threadIdx.x < 16) {
    int jj = blockIdx.x * 16 + threadIdx.x;
    double s = 0.0;
#pragma unroll
    for (int q = 0; q < 16; ++q) s += red[q][threadIdx.x];
    if (bias) s += (double)bias[jj];
    if (outd) outd[b * N + jj] = s;
    if (outf) outf[b * N + jj] = (float)s;
  }
}

// ---------- GEMV (f64 A)
__global__ __launch_bounds__(256) void k_gemv_dA(const double* __restrict__ A,
                                                 const float* __restrict__ W,
                                                 const float* __restrict__ bias,
                                                 double* __restrict__ outd,
                                                 float* __restrict__ outf,
                                                 int K, int N) {
  __shared__ double sA[D_];              // 8 KB
  int b = blockIdx.y;
  for (int i = threadIdx.x; i < K; i += 256) sA[i] = A[b * K + i];
  __syncthreads();
  int jl = threadIdx.x & 15, ks = threadIdx.x >> 4;
  int j  = blockIdx.x * 16 + jl;
  int klen = K >> 4;
  const double* Ar = sA + ks * klen;
  const float*  Wp = W + (size_t)(ks * klen) * N + j;
  double acc = 0.0;
#pragma unroll 8
  for (int kk = 0; kk < klen; ++kk)
    acc += Ar[kk] * (double)Wp[(size_t)kk * N];
  __shared__ double red[16][16];
  red[ks][jl] = acc;
  __syncthreads();
  if (threadIdx.x < 16) {
    int jj = blockIdx.x * 16 + threadIdx.x;
    double s = 0.0;
#pragma unroll
    for (int q = 0; q < 16; ++q) s += red[q][threadIdx.x];
    if (bias) s += (double)bias[jj];
    if (outd) outd[b * N + jj] = s;
    if (outf) outf[b * N + jj] = (float)s;
  }
}

// ---------- s = att @ W_cls + b_cls (f64); out0 = sigmoid(s); mask = s>0
__global__ __launch_bounds__(256) void k_cont(const double* __restrict__ att,
                                              const float* __restrict__ Wcls,
                                              const float* __restrict__ bcls,
                                              unsigned char* __restrict__ maskb,
                                              float* __restrict__ out0) {
  int vl = threadIdx.x & 15, ks = threadIdx.x >> 4;
  int v  = blockIdx.x * 16 + vl;
  int vc = v < V_ ? v : V_ - 1;
  double acc[B_];
#pragma unroll
  for (int b = 0; b < B_; ++b) acc[b] = 0.0;
  int k0 = ks * 64;
#pragma unroll 8
  for (int kk = 0; kk < 64; ++kk) {
    int k = k0 + kk;
    double w = (double)Wcls[(size_t)k * V_ + vc];
#pragma unroll
    for (int b = 0; b < B_; ++b) acc[b] += att[b * D_ + k] * w;
  }
  __shared__ double red[16][B_][16];
#pragma unroll
  for (int b = 0; b < B_; ++b) red[ks][b][vl] = acc[b];
  __syncthreads();
  int b = threadIdx.x >> 4;
  double s = 0.0;
#pragma unroll
  for (int q = 0; q < 16; ++q) s += red[q][b][vl];
  if (v < V_) {
    s += (double)bcls[v];
    maskb[b * V_ + v] = (s > 0.0) ? 1 : 0;
    out0[b * V_ + v] = (float)(1.0 / (1.0 + exp(-s)));
  }
}

// ---------- prep: WT (padded W_ft2^T), WbT (W_ft1 bottom^T), PB (pos as bf16)
__global__ __launch_bounds__(256) void k_prep(const float* __restrict__ Wft2,
                                              const float* __restrict__ Wft1,
                                              const float* __restrict__ pos,
                                              ushort_t* __restrict__ WT,
                                              ushort_t* __restrict__ WbT,
                                              ushort_t* __restrict__ PB) {
  int i = blockIdx.x * 256 + threadIdx.x;
  if (i < CPAD * HID_) {
    int c = i >> 9, k = i & (HID_ - 1);
    WT[i] = (c < C_) ? f2b(Wft2[(size_t)k * C_ + c]) : (ushort_t)0;
    return;
  }
  i -= CPAD * HID_;
  if (i < HID_ * PD_) {
    int k = i & (HID_ - 1), pd = i >> 9;
    WbT[(size_t)k * PD_ + pd] = f2b(Wft1[(size_t)(D_ + pd) * HID_ + k]);
    return;
  }
  i -= HID_ * PD_;
  if (i < V_ * PD_) PB[i] = f2b(pos[i]);
}

// ---------- PP[v][k_out] = PB @ WbT^T (bf16 MFMA, direct frag loads) --------
// grid (108, 8), 4 waves; wave = 16 v x 64 k_out, K = pd = 256.
__global__ __launch_bounds__(256) void k_pproj(const ushort_t* __restrict__ PB,
                                               const ushort_t* __restrict__ WbT,
                                               ushort_t* __restrict__ PP) {
  int wave = threadIdx.x >> 6, lane = threadIdx.x & 63;
  int q = lane >> 4, l15 = lane & 15;
  int m0 = blockIdx.x * 64 + wave * 16;        // v tile
  int n0 = blockIdx.y * 64;                    // k_out tile
  int vc = m0 + l15; vc = vc < V_ ? vc : V_ - 1;
  const ushort_t* pb = PB + (size_t)vc * PD_;
  float4_ acc[4] = {};
#pragma unroll 2
  for (int kt = 0; kt < 8; ++kt) {
    int jb = kt * 32 + q * 8;
    short8 a = *(const short8*)(pb + jb);
#pragma unroll
    for (int nf = 0; nf < 4; ++nf) {
      int n = n0 + nf * 16 + l15;
      short8 bfr = *(const short8*)(WbT + (size_t)n * PD_ + jb);
      acc[nf] = MFMA16(a, bfr, acc[nf], 0, 0, 0);
    }
  }
  int v0w = m0 + q * 4;
#pragma unroll
  for (int nf = 0; nf < 4; ++nf)
#pragma unroll
    for (int r = 0; r < 4; ++r)
      PP[(size_t)(v0w + r) * HID_ + (n0 + nf * 16 + l15)] = f2b(acc[nf][r]);
}

// ---------- main: preds^T[b] = W_ft2^T @ relu(attproj[b] + PP^T) ------------
// grid (54, 8): v-tile 128, batch pair. WT k-slice double-buffered in LDS.
__global__ __launch_bounds__(256, 2) void k_main(const ushort_t* __restrict__ WT,
                                                 const ushort_t* __restrict__ PP,
                                                 const float* __restrict__ attproj,
                                                 const unsigned char* __restrict__ maskb,
                                                 const float* __restrict__ bft2,
                                                 float* __restrict__ out1) {
  __shared__ ushort_t swt[2][CPAD * 32];   // 2 x 9216 B
  __shared__ float attp[2][HID_];          // 4 KB
  int b0 = blockIdx.y * 2;
  int wave = threadIdx.x >> 6, lane = threadIdx.x & 63;
  int q = lane >> 4, l15 = lane & 15;
  int vbase = blockIdx.x * 128 + wave * 32;

  for (int i = threadIdx.x; i < 2 * HID_; i += 256)
    attp[i >> 9][i & (HID_ - 1)] = attproj[(b0 + (i >> 9)) * HID_ + (i & (HID_ - 1))];

  // cooperative WT slice stage: slice kt = rows [0,144) x k [kt*32, kt*32+32)
  auto stage = [&](int kt, int buf) {
#pragma unroll
    for (int ii = 0; ii < 3; ++ii) {
      int i = ii * 256 + threadIdx.x;
      if (i < 576) {
        int row = i >> 2, seg = i & 3;
        *(short8*)&swt[buf][row * 32 + seg * 8] =
            *(const short8*)(WT + (size_t)row * HID_ + kt * 32 + seg * 8);
      }
    }
  };
  stage(0, 0);

  const ushort_t* pbase0 = PP + (size_t)(vbase + l15) * HID_;
  const ushort_t* pbase1 = PP + (size_t)(vbase + 16 + l15) * HID_;
  short8 pcur[2];
  pcur[0] = *(const short8*)(pbase0 + q * 8);
  pcur[1] = *(const short8*)(pbase1 + q * 8);
  __syncthreads();

  float4_ acc[2][9][2] = {};
  for (int kt = 0; kt < 16; ++kt) {
    int buf = kt & 1;
    int kb = kt * 32 + q * 8;
    if (kt < 15) stage(kt + 1, buf ^ 1);
    short8 pnext[2] = {pcur[0], pcur[1]};
    if (kt < 15) {
      pnext[0] = *(const short8*)(pbase0 + kb + 32);
      pnext[1] = *(const short8*)(pbase1 + kb + 32);
    }
    float pf[2][8];
#pragma unroll
    for (int nf = 0; nf < 2; ++nf)
#pragma unroll
      for (int jj = 0; jj < 8; ++jj)
        pf[nf][jj] = b2f((ushort_t)pcur[nf][jj]);
    float af[2][8];
#pragma unroll
    for (int bb = 0; bb < 2; ++bb) {
      float4_ a0 = *(const float4_*)&attp[bb][kb];
      float4_ a1 = *(const float4_*)&attp[bb][kb + 4];
#pragma unroll
      for (int e = 0; e < 4; ++e) { af[bb][e] = a0[e]; af[bb][4 + e] = a1[e]; }
    }
    short8 bfr[2][2];
#pragma unroll
    for (int bb = 0; bb < 2; ++bb)
#pragma unroll
      for (int nf = 0; nf < 2; ++nf) {
        unsigned int uu[4];
#pragma unroll
        for (int jj = 0; jj < 8; jj += 2) {
          float h0 = af[bb][jj]     + pf[nf][jj];
          float h1 = af[bb][jj + 1] + pf[nf][jj + 1];
          h0 = h0 > 0.f ? h0 : 0.f;
          h1 = h1 > 0.f ? h1 : 0.f;
          uu[jj >> 1] = f22u(h0, h1);
        }
        __builtin_memcpy(&bfr[bb][nf], uu, 16);
      }
#pragma unroll
    for (int mt = 0; mt < 9; ++mt) {
      short8 a = *(const short8*)&swt[buf][(mt * 16 + l15) * 32 + q * 8];
      acc[0][mt][0] = MFMA16(a, bfr[0][0], acc[0][mt][0], 0, 0, 0);
      acc[0][mt][1] = MFMA16(a, bfr[0][1], acc[0][mt][1], 0, 0, 0);
      acc[1][mt][0] = MFMA16(a, bfr[1][0], acc[1][mt][0], 0, 0, 0);
      acc[1][mt][1] = MFMA16(a, bfr[1][1], acc[1][mt][1], 0, 0, 0);
    }
    pcur[0] = pnext[0];
    pcur[1] = pnext[1];
    __syncthreads();
  }

  bool mk[2][2];
  int  nn[2];
#pragma unroll
  for (int nf = 0; nf < 2; ++nf) {
    int n = vbase + nf * 16 + l15;
    nn[nf] = n;
    int ncl = n < V_ ? n : V_ - 1;
    mk[0][nf] = (n < V_) && (maskb[(b0 + 0) * V_ + ncl] != 0);
    mk[1][nf] = (n < V_) && (maskb[(b0 + 1) * V_ + ncl] != 0);
  }
#pragma unroll
  for (int bb = 0; bb < 2; ++bb) {
    float* ob = out1 + (size_t)(b0 + bb) * C_ * V_;
#pragma unroll
    for (int mt = 0; mt < 9; ++mt)
#pragma unroll
      for (int r = 0; r < 4; ++r) {
        int c = mt * 16 + q * 4 + r;
        if (c < C_) {
          float bias = bft2[c];
#pragma unroll
          for (int nf = 0; nf < 2; ++nf)
            if (nn[nf] < V_) {
              float val = mk[bb][nf] ? acc[bb][mt][nf][r] + bias : 0.f;
              ob[(size_t)c * V_ + nn[nf]] = val;
            }
        }
      }
  }
}

extern "C" void kernel_launch(void* const* d_in, const int* in_sizes, int n_in,
                              void* d_out, int out_size, void* d_ws, size_t ws_size,
                              hipStream_t stream) {
  const float* features  = (const float*)d_in[0];
  // W_scene/b_scene/Wq/Wk are mathematically dead: softmax over a length-1
  // sequence is identically 1, so att = (part @ Wv) @ Wo.
  const float* W_contact = (const float*)d_in[3];
  const float* b_contact = (const float*)d_in[4];
  const float* Wv        = (const float*)d_in[7];
  const float* Wo        = (const float*)d_in[8];
  const float* W_cls     = (const float*)d_in[9];
  const float* b_cls     = (const float*)d_in[10];
  const float* pos_emb   = (const float*)d_in[11];
  const float* W_ft1     = (const float*)d_in[12];
  const float* b_ft1     = (const float*)d_in[13];
  const float* W_ft2     = (const float*)d_in[14];
  const float* b_ft2     = (const float*)d_in[15];

  char* ws = (char*)d_ws;
  double*        part  = (double*)(ws);                 // dead after 2nd gemv
  unsigned char* maskb = (unsigned char*)(ws);          // written later by k_cont
  double*        vv    = (double*)(ws + 131072);
  double*        att   = (double*)(ws + 262144);
  float*         attpj = (float*)(ws + 393216);
  ushort_t*      wt    = (ushort_t*)(ws + 425984);      // 147456 B
  ushort_t*      wbt   = (ushort_t*)(ws + 573440);      // 262144 B
  ushort_t*      pp    = (ushort_t*)(ws + 835584);      // 7077888 B
  ushort_t*      pb    = (ushort_t*)(ws + 7913472);     // 3527680 B -> ~11.4 MB

  float* out0 = (float*)d_out;
  float* out1 = out0 + (size_t)B_ * V_;

  // prep total elems: CPAD*HID + HID*PD + V*PD = 1,968,640 -> 7690 blocks
  k_prep<<<7690, 256, 0, stream>>>(W_ft2, W_ft1, pos_emb, wt, wbt, pb);
  k_pproj<<<dim3(108, 8), 256, 0, stream>>>(pb, wbt, pp);
  k_gemv_fA<<<dim3(64, 16), 256, 0, stream>>>(features, W_contact, b_contact, part, nullptr, DF_, D_);
  k_gemv_dA<<<dim3(64, 16), 256, 0, stream>>>(part, Wv, nullptr, vv, nullptr, D_, D_);
  k_gemv_dA<<<dim3(64, 16), 256, 0, stream>>>(vv, Wo, nullptr, att, nullptr, D_, D_);
  k_gemv_dA<<<dim3(32, 16), 256, 0, stream>>>(att, W_ft1, b_ft1, nullptr, attpj, D_, HID_);
  k_cont<<<432, 256, 0, stream>>>(att, W_cls, b_cls, maskb, out0);
  k_main<<<dim3(54, 8), 256, 0, stream>>>(wt, pp, attpj, maskb, b_ft2, out1);
}